// Round 6
// baseline (126.543 us; speedup 1.0000x reference)
//
#include <hip/hip_runtime.h>

#define NF 128
#define NBMAX 2048     // max 64-row buckets (N <= 131072)
#define RPB 64         // rows per bucket (bucketize granularity)
#define RPH 32         // rows per fused block (half bucket)
#define CAP 1408       // per-bucket edge capacity (Poisson(1024) + 12 sigma)
#define CAPH 768       // per-half-bucket capacity (Poisson(512) + 11 sigma)
#define CHUNK 8192     // edges per bucketize role-block
#define PREP_THREADS 1024

typedef unsigned int uint;
typedef unsigned short ushort;
typedef __attribute__((ext_vector_type(8))) short bf16x8;
typedef __attribute__((ext_vector_type(4))) float f32x4;

__device__ inline ushort f32_to_bf16(float f) {
    uint u = __float_as_uint(f);
    return (ushort)((u + 0x7FFFu + ((u >> 16) & 1u)) >> 16);
}

// ---------------- mega-prep: convert_x || prep_Wfrag || bucketize ----------------
// Wfrag layout: frag f=(kc*8+nf), lane l, j: Wfrag[f*512 + l*8 + j] =
//   bf16(W[(kc*32+(l>>4)*8+j)*128 + nf*16+(l&15)])
__global__ __launch_bounds__(PREP_THREADS) void prep_kernel(
    const float* __restrict__ x, ushort* __restrict__ xh, int total8,
    const float* __restrict__ W, ushort* __restrict__ Wfrag,
    const int* __restrict__ erow, const int* __restrict__ ecol,
    int* __restrict__ bcur, uint* __restrict__ bbuf, int E, int NB, int CB) {
    __shared__ int pos[NBMAX];
    const int b = blockIdx.x;
    const int tid = threadIdx.x;

    if (b < CB) {
        int base = b * (PREP_THREADS * 4) + tid;
#pragma unroll
        for (int p = 0; p < 4; ++p) {
            int i = base + p * PREP_THREADS;
            if (i < total8) {
                const float4 a = ((const float4*)x)[i * 2];
                const float4 c = ((const float4*)x)[i * 2 + 1];
                uint4 o;
                o.x = (uint)f32_to_bf16(a.x) | ((uint)f32_to_bf16(a.y) << 16);
                o.y = (uint)f32_to_bf16(a.z) | ((uint)f32_to_bf16(a.w) << 16);
                o.z = (uint)f32_to_bf16(c.x) | ((uint)f32_to_bf16(c.y) << 16);
                o.w = (uint)f32_to_bf16(c.z) | ((uint)f32_to_bf16(c.w) << 16);
                ((uint4*)xh)[i] = o;
            }
        }
    } else if (b == CB) {
        for (int idx = tid; idx < 64 * 64 * 8; idx += PREP_THREADS) {
            int f = idx >> 9, l = (idx >> 3) & 63, j = idx & 7;
            int kc = f >> 3, nf = f & 7;
            int k = kc * 32 + ((l >> 4) << 3) + j;
            int col = nf * 16 + (l & 15);
            Wfrag[idx] = f32_to_bf16(W[(size_t)k * 128 + col]);
        }
    } else {
        const int start = (b - CB - 1) * CHUNK;
        const int end = min(start + CHUNK, E);
        for (int q = tid; q < NB; q += PREP_THREADS) pos[q] = 0;
        __syncthreads();
        for (int i = start + tid; i < end; i += PREP_THREADS) atomicAdd(&pos[erow[i] >> 6], 1);
        __syncthreads();
        for (int q = tid; q < NB; q += PREP_THREADS) {
            int c = pos[q];
            pos[q] = (c > 0) ? atomicAdd(&bcur[q], c) : 0;
        }
        __syncthreads();
        for (int i = start + tid; i < end; i += PREP_THREADS) {
            int r = erow[i], c = ecol[i];
            int bkt = r >> 6;
            int p = atomicAdd(&pos[bkt], 1);
            bbuf[(size_t)bkt * CAP + p] = ((uint)(r & 63) << 17) | (uint)c;
        }
    }
}

// ---------------- fused: sort + bf16 gather-mean + MFMA GEMM + ReLU --------------
// One block per HALF-bucket (32 rows): LDS ~19.7KB -> 8 blocks/CU (32 waves/CU,
// 100% wave cap; the 64-row version's 39.4KB capped at 50% and measured 32%).
// Block filter-scans its bucket's packed words, keeping only its half's rows.
__global__ __launch_bounds__(256) void fused_kernel(
    const ushort* __restrict__ xh, const int* __restrict__ bcur,
    const uint* __restrict__ bbuf, const ushort* __restrict__ Wfrag,
    float* __restrict__ out, int N) {
    __shared__ int offs[RPH + 1];
    __shared__ int cur[RPH];
    __shared__ int cols[CAPH];
    __shared__ ushort nl[RPH * 256];   // 16KB, byte ^= (row&7)<<4 swizzle
    const int b = blockIdx.x >> 1;
    const int half = blockIdx.x & 1;
    const int tid = threadIdx.x;
    const int cnt = min(bcur[b], CAP);
    const uint* buf = bbuf + (size_t)b * CAP;

    if (tid < RPH) cur[tid] = 0;
    __syncthreads();
    for (int i = tid; i < cnt; i += 256) {
        int r = (int)(buf[i] >> 17);
        if ((r >> 5) == half) atomicAdd(&cur[r & 31], 1);
    }
    __syncthreads();
    if (tid == 0) {
        int run = 0;
        offs[0] = 0;
        for (int r = 0; r < RPH; ++r) { run += cur[r]; offs[r + 1] = min(run, CAPH); }
    }
    __syncthreads();
    if (tid < RPH) cur[tid] = offs[tid];
    __syncthreads();
    for (int i = tid; i < cnt; i += 256) {
        uint v = buf[i];
        int r = (int)(v >> 17);
        if ((r >> 5) == half) {
            int p = atomicAdd(&cur[r & 31], 1);
            if (p < CAPH) cols[p] = (int)(v & 0x1FFFFu);
        }
    }
    __syncthreads();

    // gather: 16 units x 16 lanes; each unit does rows {u, u+16}
    const int unit = tid >> 4, lane16 = tid & 15;
    for (int r = unit; r < RPH; r += 16) {
        int j0 = offs[r], j1 = offs[r + 1];
        float a0 = 0.f, a1 = 0.f, a2 = 0.f, a3 = 0.f, a4 = 0.f, a5 = 0.f, a6 = 0.f, a7 = 0.f;
        int j = j0;
        for (; j + 1 < j1; j += 2) {     // 2-way MLP
            int c0 = cols[j], c1 = cols[j + 1];
            uint4 v0 = *(const uint4*)&xh[(size_t)c0 * NF + lane16 * 8];
            uint4 v1 = *(const uint4*)&xh[(size_t)c1 * NF + lane16 * 8];
            a0 += __uint_as_float(v0.x << 16) + __uint_as_float(v1.x << 16);
            a1 += __uint_as_float(v0.x & 0xFFFF0000u) + __uint_as_float(v1.x & 0xFFFF0000u);
            a2 += __uint_as_float(v0.y << 16) + __uint_as_float(v1.y << 16);
            a3 += __uint_as_float(v0.y & 0xFFFF0000u) + __uint_as_float(v1.y & 0xFFFF0000u);
            a4 += __uint_as_float(v0.z << 16) + __uint_as_float(v1.z << 16);
            a5 += __uint_as_float(v0.z & 0xFFFF0000u) + __uint_as_float(v1.z & 0xFFFF0000u);
            a6 += __uint_as_float(v0.w << 16) + __uint_as_float(v1.w << 16);
            a7 += __uint_as_float(v0.w & 0xFFFF0000u) + __uint_as_float(v1.w & 0xFFFF0000u);
        }
        if (j < j1) {
            uint4 v0 = *(const uint4*)&xh[(size_t)cols[j] * NF + lane16 * 8];
            a0 += __uint_as_float(v0.x << 16);
            a1 += __uint_as_float(v0.x & 0xFFFF0000u);
            a2 += __uint_as_float(v0.y << 16);
            a3 += __uint_as_float(v0.y & 0xFFFF0000u);
            a4 += __uint_as_float(v0.z << 16);
            a5 += __uint_as_float(v0.z & 0xFFFF0000u);
            a6 += __uint_as_float(v0.w << 16);
            a7 += __uint_as_float(v0.w & 0xFFFF0000u);
        }
        float sc = 1.0f / (float)(j1 - j0 + 1);
        bf16x8 t;
        t[0] = (short)f32_to_bf16(a0 * sc); t[1] = (short)f32_to_bf16(a1 * sc);
        t[2] = (short)f32_to_bf16(a2 * sc); t[3] = (short)f32_to_bf16(a3 * sc);
        t[4] = (short)f32_to_bf16(a4 * sc); t[5] = (short)f32_to_bf16(a5 * sc);
        t[6] = (short)f32_to_bf16(a6 * sc); t[7] = (short)f32_to_bf16(a7 * sc);
        uint boff = ((uint)r * 512 + (uint)lane16 * 16) ^ ((uint)(r & 7) << 4);
        *(bf16x8*)((char*)nl + boff) = t;
    }
    __syncthreads();

    // GEMM: 4 waves, each 16 rows x 64 cols (mf = wid>>1, col-quad = wid&1)
    const int wid = tid >> 6, lane = tid & 63;
    const int lm = lane & 15;
    const int lkb = (lane >> 4) * 8;
    const int mf = wid >> 1, nquad = wid & 1;
    const int lrow = mf * 16 + lm;               // local row 0..31
    int grow = b * RPB + half * RPH + lrow;
    if (grow >= N) grow = N - 1;                 // clamp: values discarded at store

    f32x4 acc[4] = {};
#pragma unroll
    for (int kc = 0; kc < 8; ++kc) {
        bf16x8 aR;
        if (kc < 4) {
            aR = *(const bf16x8*)&xh[(size_t)grow * NF + kc * 32 + lkb];
        } else {
            uint boff = ((uint)lrow * 512 + (uint)((kc - 4) * 32 + lkb) * 2)
                        ^ ((uint)(lrow & 7) << 4);
            aR = *(const bf16x8*)((const char*)nl + boff);
        }
        const ushort* wf = &Wfrag[(size_t)(kc * 8 + nquad * 4) * 512 + (size_t)lane * 8];
#pragma unroll
        for (int nf = 0; nf < 4; ++nf) {
            bf16x8 bR = *(const bf16x8*)(wf + (size_t)nf * 512);
            acc[nf] = __builtin_amdgcn_mfma_f32_16x16x32_bf16(aR, bR, acc[nf], 0, 0, 0);
        }
    }

    // epilogue: ReLU + store (C layout: col=lane&15, row=(lane>>4)*4+reg)
    const int rb = mf * 16 + (lane >> 4) * 4;
#pragma unroll
    for (int j = 0; j < 4; ++j) {
        int row = b * RPB + half * RPH + rb + j;
        if (row < N) {
#pragma unroll
            for (int nf = 0; nf < 4; ++nf)
                out[(size_t)row * NF + (nquad * 4 + nf) * 16 + lm] = fmaxf(acc[nf][j], 0.f);
        }
    }
}

// ---------------- launcher ----------------
extern "C" void kernel_launch(void* const* d_in, const int* in_sizes, int n_in,
                              void* d_out, int out_size, void* d_ws, size_t ws_size,
                              hipStream_t stream) {
    const float* x    = (const float*)d_in[0];
    const int*   erow = (const int*)d_in[1];
    const int*   ecol = (const int*)d_in[2];
    const float* W    = (const float*)d_in[3];
    const int N = in_sizes[0] / NF;
    const int E = in_sizes[1];
    float* out = (float*)d_out;

    const int NB = (N + RPB - 1) / RPB;
    const int total8 = N * NF / 8;
    const int CB = (total8 + PREP_THREADS * 4 - 1) / (PREP_THREADS * 4);
    const int BB = (E + CHUNK - 1) / CHUNK;

    // ws layout: xh[N*NF bf16] | Wfrag[64*512 bf16] | bcur[NBMAX] | bbuf[NB*CAP] (~34.5 MB)
    char* ws = (char*)d_ws;
    ushort* xh    = (ushort*)ws;
    ushort* Wfrag = (ushort*)(ws + (size_t)N * NF * 2);
    int*    bcur  = (int*)((char*)Wfrag + 64 * 512 * 2);
    uint*   bbuf  = (uint*)(bcur + NBMAX);

    hipMemsetAsync(bcur, 0, (size_t)NB * sizeof(int), stream);
    prep_kernel<<<CB + 1 + BB, PREP_THREADS, 0, stream>>>(
        x, xh, total8, W, Wfrag, erow, ecol, bcur, bbuf, E, NB, CB);
    fused_kernel<<<NB * 2, 256, 0, stream>>>(xh, bcur, bbuf, Wfrag, out, N);
}

// Round 8
// 103.541 us; speedup vs baseline: 1.2222x; 1.2222x over previous
//
#include <hip/hip_runtime.h>

#define NF 128
#define NBMAX 2048     // max 64-row buckets (N <= 131072)
#define RPB 64         // rows per bucket (bucketize granularity)
#define RPH 32         // rows per fused block (half bucket)
#define CAP 1408       // per-bucket edge capacity (Poisson(1024) + 12 sigma)
#define CAPH 768       // per-half-bucket capacity (Poisson(512) + 11 sigma)
#define CHUNK 8192     // edges per bucketize role-block
#define PREP_THREADS 1024

typedef unsigned int uint;
typedef unsigned short ushort;
typedef unsigned char uchar;
typedef __attribute__((ext_vector_type(8))) short bf16x8;
typedef __attribute__((ext_vector_type(4))) float f32x4;
typedef __attribute__((ext_vector_type(2))) float f32x2;

__device__ inline ushort f32_to_bf16(float f) {
    uint u = __float_as_uint(f);
    return (ushort)((u + 0x7FFFu + ((u >> 16) & 1u)) >> 16);
}

// ---------------- mega-prep: convert x->xq(fp8) || prep_Wfrag || bucketize ------
// Wfrag layout: frag f=(kc*8+nf), lane l, j: Wfrag[f*512 + l*8 + j] =
//   bf16(W[(kc*32+(l>>4)*8+j)*128 + nf*16+(l&15)])
__global__ __launch_bounds__(PREP_THREADS) void prep_kernel(
    const float* __restrict__ x, uchar* __restrict__ xq, int total8,
    const float* __restrict__ W, ushort* __restrict__ Wfrag,
    const int* __restrict__ erow, const int* __restrict__ ecol,
    int* __restrict__ bcur, uint* __restrict__ bbuf, int E, int NB, int CB) {
    __shared__ int pos[NBMAX];
    const int b = blockIdx.x;
    const int tid = threadIdx.x;

    if (b < CB) {
        // ---- convert x (f32) -> xq (fp8 e4m3, RNE via v_cvt_pk_fp8_f32) ----
        int base = b * (PREP_THREADS * 4) + tid;
#pragma unroll
        for (int p = 0; p < 4; ++p) {
            int i = base + p * PREP_THREADS;
            if (i < total8) {
                const float4 a = ((const float4*)x)[i * 2];
                const float4 c = ((const float4*)x)[i * 2 + 1];
                int q0 = __builtin_amdgcn_cvt_pk_fp8_f32(a.x, a.y, 0, false);
                q0 = __builtin_amdgcn_cvt_pk_fp8_f32(a.z, a.w, q0, true);
                int q1 = __builtin_amdgcn_cvt_pk_fp8_f32(c.x, c.y, 0, false);
                q1 = __builtin_amdgcn_cvt_pk_fp8_f32(c.z, c.w, q1, true);
                ((uint2*)xq)[i] = make_uint2((uint)q0, (uint)q1);
            }
        }
    } else if (b == CB) {
        // ---- W -> fragment-ordered bf16 Wfrag ----
        for (int idx = tid; idx < 64 * 64 * 8; idx += PREP_THREADS) {
            int f = idx >> 9, l = (idx >> 3) & 63, j = idx & 7;
            int kc = f >> 3, nf = f & 7;
            int k = kc * 32 + ((l >> 4) << 3) + j;
            int col = nf * 16 + (l & 15);
            Wfrag[idx] = f32_to_bf16(W[(size_t)k * 128 + col]);
        }
    } else {
        // ---- bucketize an 8192-edge chunk ----
        const int start = (b - CB - 1) * CHUNK;
        const int end = min(start + CHUNK, E);
        for (int q = tid; q < NB; q += PREP_THREADS) pos[q] = 0;
        __syncthreads();
        for (int i = start + tid; i < end; i += PREP_THREADS) atomicAdd(&pos[erow[i] >> 6], 1);
        __syncthreads();
        for (int q = tid; q < NB; q += PREP_THREADS) {
            int c = pos[q];
            pos[q] = (c > 0) ? atomicAdd(&bcur[q], c) : 0;
        }
        __syncthreads();
        for (int i = start + tid; i < end; i += PREP_THREADS) {
            int r = erow[i], c = ecol[i];
            int bkt = r >> 6;
            int p = atomicAdd(&pos[bkt], 1);
            bbuf[(size_t)bkt * CAP + p] = ((uint)(r & 63) << 17) | (uint)c;
        }
    }
}

// decode 16 fp8 (uint4) -> f32 accumulate (cvt_pk returns ext-vector: use [i])
#define DECADD(v)                                                            \
    {                                                                        \
        f32x2 t0 = __builtin_amdgcn_cvt_pk_f32_fp8((int)(v).x, false);       \
        f32x2 t1 = __builtin_amdgcn_cvt_pk_f32_fp8((int)(v).x, true);        \
        f32x2 t2 = __builtin_amdgcn_cvt_pk_f32_fp8((int)(v).y, false);       \
        f32x2 t3 = __builtin_amdgcn_cvt_pk_f32_fp8((int)(v).y, true);        \
        f32x2 t4 = __builtin_amdgcn_cvt_pk_f32_fp8((int)(v).z, false);       \
        f32x2 t5 = __builtin_amdgcn_cvt_pk_f32_fp8((int)(v).z, true);        \
        f32x2 t6 = __builtin_amdgcn_cvt_pk_f32_fp8((int)(v).w, false);       \
        f32x2 t7 = __builtin_amdgcn_cvt_pk_f32_fp8((int)(v).w, true);        \
        acc[0] += t0[0];  acc[1] += t0[1];  acc[2] += t1[0];  acc[3] += t1[1];   \
        acc[4] += t2[0];  acc[5] += t2[1];  acc[6] += t3[0];  acc[7] += t3[1];   \
        acc[8] += t4[0];  acc[9] += t4[1];  acc[10] += t5[0]; acc[11] += t5[1];  \
        acc[12] += t6[0]; acc[13] += t6[1]; acc[14] += t7[0]; acc[15] += t7[1];  \
    }

// ---------------- fused: sort + fp8 gather-mean + MFMA GEMM + ReLU --------------
// One block per HALF-bucket (32 rows). Gather: 32 units x 8 lanes, one row per
// unit, 128B (uint4/lane) per neighbor -> half the bytes of the bf16 version
// (gather was service-rate bound at ~6.8 TB/s; occupancy didn't move it).
// GEMM A x-half from f32 x with in-register RNE->bf16 (same rounding as before).
__global__ __launch_bounds__(256) void fused_kernel(
    const float* __restrict__ x, const uchar* __restrict__ xq,
    const int* __restrict__ bcur, const uint* __restrict__ bbuf,
    const ushort* __restrict__ Wfrag, float* __restrict__ out, int N) {
    __shared__ int offs[RPH + 1];
    __shared__ int cur[RPH];
    __shared__ int cols[CAPH];
    __shared__ ushort nl[RPH * 256];   // row stride 512B, byte ^= (row&7)<<4 swizzle
    const int b = blockIdx.x >> 1;
    const int half = blockIdx.x & 1;
    const int tid = threadIdx.x;
    const int cnt = min(bcur[b], CAP);
    const uint* buf = bbuf + (size_t)b * CAP;

    if (tid < RPH) cur[tid] = 0;
    __syncthreads();
    for (int i = tid; i < cnt; i += 256) {
        int r = (int)(buf[i] >> 17);
        if ((r >> 5) == half) atomicAdd(&cur[r & 31], 1);
    }
    __syncthreads();
    if (tid == 0) {
        int run = 0;
        offs[0] = 0;
        for (int r = 0; r < RPH; ++r) { run += cur[r]; offs[r + 1] = min(run, CAPH); }
    }
    __syncthreads();
    if (tid < RPH) cur[tid] = offs[tid];
    __syncthreads();
    for (int i = tid; i < cnt; i += 256) {
        uint v = buf[i];
        int r = (int)(v >> 17);
        if ((r >> 5) == half) {
            int p = atomicAdd(&cur[r & 31], 1);
            if (p < CAPH) cols[p] = (int)(v & 0x1FFFFu);
        }
    }
    __syncthreads();

    // gather: 32 units x 8 lanes; unit handles exactly one row, lane 16 feats
    {
        const int r = tid >> 3, lane8 = tid & 7;
        const int j0 = offs[r], j1 = offs[r + 1];
        float acc[16];
#pragma unroll
        for (int q = 0; q < 16; ++q) acc[q] = 0.f;
        int j = j0;
        for (; j + 1 < j1; j += 2) {     // 2-way MLP
            int c0 = cols[j], c1 = cols[j + 1];
            uint4 v0 = *(const uint4*)&xq[(size_t)c0 * NF + lane8 * 16];
            uint4 v1 = *(const uint4*)&xq[(size_t)c1 * NF + lane8 * 16];
            DECADD(v0);
            DECADD(v1);
        }
        if (j < j1) {
            uint4 v0 = *(const uint4*)&xq[(size_t)cols[j] * NF + lane8 * 16];
            DECADD(v0);
        }
        float sc = 1.0f / (float)(j1 - j0 + 1);
        bf16x8 t0, t1;
#pragma unroll
        for (int q = 0; q < 8; ++q) t0[q] = (short)f32_to_bf16(acc[q] * sc);
#pragma unroll
        for (int q = 0; q < 8; ++q) t1[q] = (short)f32_to_bf16(acc[8 + q] * sc);
        uint base = (uint)r * 512 + (uint)lane8 * 32;
        uint x16 = (uint)(r & 7) << 4;
        *(bf16x8*)((char*)nl + (base ^ x16)) = t0;
        *(bf16x8*)((char*)nl + ((base + 16) ^ x16)) = t1;
    }
    __syncthreads();

    // GEMM: 4 waves, each 16 rows x 64 cols (mf = wid>>1, col-quad = wid&1)
    const int wid = tid >> 6, lane = tid & 63;
    const int lm = lane & 15;
    const int lkb = (lane >> 4) * 8;
    const int mf = wid >> 1, nquad = wid & 1;
    const int lrow = mf * 16 + lm;               // local row 0..31
    int grow = b * RPB + half * RPH + lrow;
    if (grow >= N) grow = N - 1;                 // clamp: values discarded at store

    f32x4 acc[4] = {};
#pragma unroll
    for (int kc = 0; kc < 8; ++kc) {
        bf16x8 aR;
        if (kc < 4) {
            const float4 u = *(const float4*)&x[(size_t)grow * NF + kc * 32 + lkb];
            const float4 w4 = *(const float4*)&x[(size_t)grow * NF + kc * 32 + lkb + 4];
            aR[0] = (short)f32_to_bf16(u.x);  aR[1] = (short)f32_to_bf16(u.y);
            aR[2] = (short)f32_to_bf16(u.z);  aR[3] = (short)f32_to_bf16(u.w);
            aR[4] = (short)f32_to_bf16(w4.x); aR[5] = (short)f32_to_bf16(w4.y);
            aR[6] = (short)f32_to_bf16(w4.z); aR[7] = (short)f32_to_bf16(w4.w);
        } else {
            uint boff = ((uint)lrow * 512 + (uint)((kc - 4) * 32 + lkb) * 2)
                        ^ ((uint)(lrow & 7) << 4);
            aR = *(const bf16x8*)((const char*)nl + boff);
        }
        const ushort* wf = &Wfrag[(size_t)(kc * 8 + nquad * 4) * 512 + (size_t)lane * 8];
#pragma unroll
        for (int nf = 0; nf < 4; ++nf) {
            bf16x8 bR = *(const bf16x8*)(wf + (size_t)nf * 512);
            acc[nf] = __builtin_amdgcn_mfma_f32_16x16x32_bf16(aR, bR, acc[nf], 0, 0, 0);
        }
    }

    // epilogue: ReLU + store (C layout: col=lane&15, row=(lane>>4)*4+reg)
    const int rb = mf * 16 + (lane >> 4) * 4;
#pragma unroll
    for (int j = 0; j < 4; ++j) {
        int row = b * RPB + half * RPH + rb + j;
        if (row < N) {
#pragma unroll
            for (int nf = 0; nf < 4; ++nf)
                out[(size_t)row * NF + (nquad * 4 + nf) * 16 + lm] = fmaxf(acc[nf][j], 0.f);
        }
    }
}

// ---------------- launcher ----------------
extern "C" void kernel_launch(void* const* d_in, const int* in_sizes, int n_in,
                              void* d_out, int out_size, void* d_ws, size_t ws_size,
                              hipStream_t stream) {
    const float* x    = (const float*)d_in[0];
    const int*   erow = (const int*)d_in[1];
    const int*   ecol = (const int*)d_in[2];
    const float* W    = (const float*)d_in[3];
    const int N = in_sizes[0] / NF;
    const int E = in_sizes[1];
    float* out = (float*)d_out;

    const int NB = (N + RPB - 1) / RPB;
    const int total8 = N * NF / 8;
    const int CB = (total8 + PREP_THREADS * 4 - 1) / (PREP_THREADS * 4);
    const int BB = (E + CHUNK - 1) / CHUNK;

    // ws layout: xq[N*NF fp8] | Wfrag[64*512 bf16] | bcur[NBMAX] | bbuf[NB*CAP] (~21.7 MB)
    char* ws = (char*)d_ws;
    uchar*  xq    = (uchar*)ws;
    ushort* Wfrag = (ushort*)(ws + (size_t)N * NF);
    int*    bcur  = (int*)((char*)Wfrag + 64 * 512 * 2);
    uint*   bbuf  = (uint*)(bcur + NBMAX);

    hipMemsetAsync(bcur, 0, (size_t)NB * sizeof(int), stream);
    prep_kernel<<<CB + 1 + BB, PREP_THREADS, 0, stream>>>(
        x, xq, total8, W, Wfrag, erow, ecol, bcur, bbuf, E, NB, CB);
    fused_kernel<<<NB * 2, 256, 0, stream>>>(x, xq, bcur, bbuf, Wfrag, out, N);
}